// Round 3
// baseline (178.949 us; speedup 1.0000x reference)
//
#include <hip/hip_runtime.h>
#include <hip/hip_bf16.h>
#include <cmath>

#define B_   2
#define S_   2048
#define D_   768
#define H_   12
#define HD_  64
#define WIN_ 64

typedef __bf16 bf16x8 __attribute__((ext_vector_type(8)));
typedef __bf16 bf16x4 __attribute__((ext_vector_type(4)));
typedef float  f32x4  __attribute__((ext_vector_type(4)));
typedef unsigned int u32;

// async global->LDS, 16B per lane.  LDS dest must be wave-uniform base + lane*16.
__device__ __forceinline__ void async_ld16(const void* g, void* l) {
    __builtin_amdgcn_global_load_lds(
        (__attribute__((address_space(1))) void*)(size_t)g,
        (__attribute__((address_space(3))) void*)(u32)(size_t)l,
        16, 0, 0);
}

// ---------------------------------------------------------------------------
// fp32 -> bf16 convert for hs / Wqkv / Wo (one pass)
// ---------------------------------------------------------------------------
#define NHS (B_ * S_ * D_)        // 3145728
#define NWQ (3 * D_ * D_)         // 1769472
#define NWO (D_ * D_)             //  589824

__global__ __launch_bounds__(256) void to_bf16_3(const float* __restrict__ a,
                                                 const float* __restrict__ b,
                                                 const float* __restrict__ c,
                                                 __bf16* __restrict__ oa,
                                                 __bf16* __restrict__ ob,
                                                 __bf16* __restrict__ oc) {
    const int NA = NHS / 4, NB = NWQ / 4;
    int v = blockIdx.x * 256 + threadIdx.x;
    const float* src; __bf16* dst; int idx;
    if (v < NA)           { src = a; dst = oa; idx = v; }
    else if (v < NA + NB) { src = b; dst = ob; idx = v - NA; }
    else                  { src = c; dst = oc; idx = v - NA - NB; }
    float4 x = ((const float4*)src)[idx];
    bf16x4 y = { (__bf16)x.x, (__bf16)x.y, (__bf16)x.z, (__bf16)x.w };
    *(bf16x4*)(dst + (size_t)idx * 4) = y;
}

// ---------------------------------------------------------------------------
// GEMM: C[M,N] = A[M,K] * Bw[N,K]^T, bf16 in, MFMA, async staging, BK=64
// (12 K-iterations -> half the barrier drains vs BK=32; 32 KB LDS keeps
//  3 blocks/CU, same as the VGPR cap).
// MODE 0: fp32 C out.
// MODE 1: fused RoPE on q,k -> qkv bf16 (n<1536); v -> vt bf16 transposed.
// ---------------------------------------------------------------------------
#define BM 128
#define BN 128
#define BK 64

template <int MODE>
__global__ __launch_bounds__(256) void gemm_as(const __bf16* __restrict__ A,
                                               const __bf16* __restrict__ Bw,
                                               float* __restrict__ C,
                                               __bf16* __restrict__ qkv,
                                               __bf16* __restrict__ vt,
                                               const int* __restrict__ pos,
                                               int M, int N, int K) {
    __shared__ __attribute__((aligned(16))) __bf16 As[BM * BK];
    __shared__ __attribute__((aligned(16))) __bf16 Bs[BN * BK];

    const int tid  = threadIdx.x;
    const int m0   = blockIdx.y * BM;
    const int n0   = blockIdx.x * BN;
    const int w    = tid >> 6;
    const int lane = tid & 63;
    const int wm   = (w >> 1) * 64;
    const int wn   = (w & 1) * 64;
    const int fr   = lane & 15;
    const int fq   = lane >> 4;

    f32x4 acc[4][4] = {};

    for (int k0 = 0; k0 < K; k0 += BK) {
        #pragma unroll
        for (int i = 0; i < 4; ++i) {
            int c = i * 256 + tid;          // 1024 chunks of 16B per tile
            int row = c >> 3, cc = c & 7;
            async_ld16(A  + (size_t)(m0 + row) * K + k0 + cc * 8, As + c * 8);
            async_ld16(Bw + (size_t)(n0 + row) * K + k0 + cc * 8, Bs + c * 8);
        }
        __syncthreads();

        #pragma unroll
        for (int ks = 0; ks < 2; ++ks) {
            bf16x8 af[4], bfv[4];
            #pragma unroll
            for (int t = 0; t < 4; ++t) {
                af[t]  = *(const bf16x8*)(As + (wm + t * 16 + fr) * BK + ks * 32 + fq * 8);
                bfv[t] = *(const bf16x8*)(Bs + (wn + t * 16 + fr) * BK + ks * 32 + fq * 8);
            }
            #pragma unroll
            for (int ti = 0; ti < 4; ++ti)
                #pragma unroll
                for (int tj = 0; tj < 4; ++tj)
                    acc[ti][tj] = __builtin_amdgcn_mfma_f32_16x16x32_bf16(
                        af[ti], bfv[tj], acc[ti][tj], 0, 0, 0);
        }
        __syncthreads();
    }

    // C/D layout: col = lane&15, row = (lane>>4)*4 + reg
    if (MODE == 0) {
        #pragma unroll
        for (int ti = 0; ti < 4; ++ti)
            #pragma unroll
            for (int tj = 0; tj < 4; ++tj) {
                const int col = n0 + wn + tj * 16 + fr;
                #pragma unroll
                for (int r = 0; r < 4; ++r) {
                    const int row = m0 + wm + ti * 16 + fq * 4 + r;
                    C[(size_t)row * N + col] = acc[ti][tj][r];
                }
            }
    } else {
        if (n0 < 2 * D_) {
            // fused RoPE: wave spans one 64-col head slice; pair (d, d+32)
            // lives in (acc[ti][tjp], acc[ti][tjp+2]), d = tjp*16 + fr.
            const float invf0 = __powf(10000.0f, -(float)fr * (1.0f / 32.0f));
            const float invf1 = __powf(10000.0f, -(float)(16 + fr) * (1.0f / 32.0f));
            #pragma unroll
            for (int ti = 0; ti < 4; ++ti)
                #pragma unroll
                for (int r = 0; r < 4; ++r) {
                    const int row = m0 + wm + ti * 16 + fq * 4 + r;
                    const float p = (float)pos[row];
                    float s0, c0, s1, c1;
                    sincosf(p * invf0, &s0, &c0);
                    sincosf(p * invf1, &s1, &c1);
                    const float a0 = acc[ti][0][r], a1 = acc[ti][2][r];
                    acc[ti][0][r] = a0 * c0 - a1 * s0;
                    acc[ti][2][r] = a1 * c0 + a0 * s0;
                    const float b0 = acc[ti][1][r], b1 = acc[ti][3][r];
                    acc[ti][1][r] = b0 * c1 - b1 * s1;
                    acc[ti][3][r] = b1 * c1 + b0 * s1;
                }
            #pragma unroll
            for (int ti = 0; ti < 4; ++ti)
                #pragma unroll
                for (int tj = 0; tj < 4; ++tj) {
                    const int col = n0 + wn + tj * 16 + fr;
                    #pragma unroll
                    for (int r = 0; r < 4; ++r) {
                        const int row = m0 + wm + ti * 16 + fq * 4 + r;
                        qkv[(size_t)row * (2 * D_) + col] = (__bf16)acc[ti][tj][r];
                    }
                }
        } else {             // v -> vt[b][h][d][token]
            #pragma unroll
            for (int ti = 0; ti < 4; ++ti)
                #pragma unroll
                for (int tj = 0; tj < 4; ++tj) {
                    const int col = n0 + wn + tj * 16 + fr - 2 * D_;
                    const int h = col >> 6, d = col & 63;
                    const int row0 = m0 + wm + ti * 16 + fq * 4;
                    const int bb = row0 >> 11, t0 = row0 & (S_ - 1);
                    bf16x4 pk = { (__bf16)acc[ti][tj][0], (__bf16)acc[ti][tj][1],
                                  (__bf16)acc[ti][tj][2], (__bf16)acc[ti][tj][3] };
                    *(bf16x4*)(vt + ((size_t)((bb * H_ + h) * HD_ + d)) * S_ + t0) = pk;
                }
        }
    }
}

// ---------------------------------------------------------------------------
// MFMA banded attention.  Block = 64 queries x (head, batch), 4 waves.
// LDS (48 KB -> 3 blocks/CU):
//   Ks  [2][192][32]  (12288 el, 24 KB)  -- overlaid by P after scores
//   Vts [6][64][32]   (12288 el, 24 KB)  (V^T: rows = head dim, cols = keys)
// Q frags read directly from global (16B contiguous per lane).
// ---------------------------------------------------------------------------
__global__ __launch_bounds__(256) void attn_mfma(const __bf16* __restrict__ qkv,
                                                 const __bf16* __restrict__ vt,
                                                 __bf16* __restrict__ outb) {
    __shared__ __attribute__((aligned(16))) __bf16 smem[24576];  // 48 KB
    __bf16* Ks  = smem;
    __bf16* Vts = smem + 12288;

    const int i0  = blockIdx.x * 64;
    const int h   = blockIdx.y;
    const int b   = blockIdx.z;
    const int tid = threadIdx.x;
    const int w = tid >> 6, lane = tid & 63;
    const int fr = lane & 15, fq = lane >> 4;
    const int wq0 = w * 16;

    // ---- stage K (1536 chunks), Vt (1536 chunks) via async copy ----
    #pragma unroll
    for (int i = 0; i < 6; ++i) {
        int c = i * 256 + tid;
        int ks = (i >= 3);
        int rem = c - ks * 768;
        int cc = rem & 3, row = rem >> 2;
        int j = i0 - 64 + row; j = min(max(j, 0), S_ - 1);   // clamped addr; masked later
        async_ld16(qkv + ((size_t)b * S_ + j) * (2 * D_) + D_ + h * HD_ + ks * 32 + cc * 8,
                   Ks + c * 8);
    }
    const size_t vbase = (size_t)((b * H_ + h) * HD_) * S_;
    #pragma unroll
    for (int i = 0; i < 6; ++i) {
        int c = i * 256 + tid;
        int ks = c >> 8, rem = c & 255, d = rem >> 2, cc = rem & 3;
        int key = i0 - 64 + ks * 32 + cc * 8;
        key = min(max(key, 0), S_ - 8);                      // clamped addr; masked later
        async_ld16(vt + vbase + (size_t)d * S_ + key, Vts + c * 8);
    }

    // ---- Q frags from global while staging is in flight ----
    const size_t qrow = ((size_t)b * S_ + i0 + wq0 + fr) * (2 * D_) + h * HD_;
    bf16x8 aq[2];
    aq[0] = *(const bf16x8*)(qkv + qrow + fq * 8);
    aq[1] = *(const bf16x8*)(qkv + qrow + 32 + fq * 8);

    __syncthreads();

    // ---- QK^T: S[16 q][192 keys] per wave ----
    f32x4 sc[12] = {};
    #pragma unroll
    for (int nt = 0; nt < 12; ++nt) {
        #pragma unroll
        for (int ks = 0; ks < 2; ++ks) {
            bf16x8 bk = *(const bf16x8*)(Ks + (ks * 192 + nt * 16 + fr) * 32 + fq * 8);
            sc[nt] = __builtin_amdgcn_mfma_f32_16x16x32_bf16(aq[ks], bk, sc[nt], 0, 0, 0);
        }
    }

    // ---- mask + softmax (C layout: col j <- fr, rows q <- fq*4+r) ----
    float mx[4] = { -1e30f, -1e30f, -1e30f, -1e30f };
    #pragma unroll
    for (int nt = 0; nt < 12; ++nt) {
        const int jr = nt * 16 + fr;          // key - (i0-64)
        const int j  = i0 - 64 + jr;
        const bool jv = (j >= 0) && (j < S_);
        #pragma unroll
        for (int r = 0; r < 4; ++r) {
            const int ir = wq0 + fq * 4 + r + 64;   // query - (i0-64)
            const int dd = ir - jr;
            const bool v = jv && (dd <= WIN_) && (dd >= -WIN_);
            sc[nt][r] = v ? sc[nt][r] * 0.125f : -1e30f;
            mx[r] = fmaxf(mx[r], sc[nt][r]);
        }
    }
    #pragma unroll
    for (int r = 0; r < 4; ++r)
        #pragma unroll
        for (int off = 1; off < 16; off <<= 1)
            mx[r] = fmaxf(mx[r], __shfl_xor(mx[r], off, 64));

    float sm[4] = { 0.f, 0.f, 0.f, 0.f };
    #pragma unroll
    for (int nt = 0; nt < 12; ++nt)
        #pragma unroll
        for (int r = 0; r < 4; ++r) {
            float e = __expf(sc[nt][r] - mx[r]);
            sc[nt][r] = e;
            sm[r] += e;
        }
    #pragma unroll
    for (int r = 0; r < 4; ++r) {
        #pragma unroll
        for (int off = 1; off < 16; off <<= 1)
            sm[r] += __shfl_xor(sm[r], off, 64);
        sm[r] = 1.0f / sm[r];
    }

    __syncthreads();   // all waves done reading Ks before P overwrites it

    // ---- write normalized P (bf16) into per-wave [6][16][32] panels over Ks ----
    __bf16* Pw = Ks + w * 3072;
    #pragma unroll
    for (int nt = 0; nt < 12; ++nt) {
        const int ks = nt >> 1, kk = (nt & 1) * 16 + fr;
        #pragma unroll
        for (int r = 0; r < 4; ++r)
            Pw[(ks * 16 + fq * 4 + r) * 32 + kk] = (__bf16)(sc[nt][r] * sm[r]);
    }

    // ---- O = P * V  (A = P [q][k] panels, B = V^T panels) ----
    f32x4 oacc[4] = {};
    #pragma unroll
    for (int ks = 0; ks < 6; ++ks) {
        bf16x8 ap = *(const bf16x8*)(Pw + (ks * 16 + fr) * 32 + fq * 8);
        #pragma unroll
        for (int nt2 = 0; nt2 < 4; ++nt2) {
            bf16x8 bv = *(const bf16x8*)(Vts + (ks * 64 + nt2 * 16 + fr) * 32 + fq * 8);
            oacc[nt2] = __builtin_amdgcn_mfma_f32_16x16x32_bf16(ap, bv, oacc[nt2], 0, 0, 0);
        }
    }

    const size_t obase = ((size_t)b * S_ + i0 + wq0) * D_ + h * HD_;
    #pragma unroll
    for (int nt2 = 0; nt2 < 4; ++nt2)
        #pragma unroll
        for (int r = 0; r < 4; ++r)
            outb[obase + (size_t)(fq * 4 + r) * D_ + nt2 * 16 + fr] = (__bf16)oacc[nt2][r];
}

// ---------------------------------------------------------------------------
extern "C" void kernel_launch(void* const* d_in, const int* in_sizes, int n_in,
                              void* d_out, int out_size, void* d_ws, size_t ws_size,
                              hipStream_t stream) {
    const float* hs   = (const float*)d_in[0];
    const float* wqkv = (const float*)d_in[1];
    const float* wo   = (const float*)d_in[2];
    const int*   pos  = (const int*)d_in[4];
    float* out = (float*)d_out;

    __bf16* base    = (__bf16*)d_ws;
    __bf16* hs_bf   = base;                          // 3,145,728
    __bf16* wqkv_bf = hs_bf + NHS;                   // 1,769,472
    __bf16* wo_bf   = wqkv_bf + NWQ;                 //   589,824
    __bf16* qkv     = wo_bf + NWO;                   // 4096*1536
    __bf16* vt      = qkv + (size_t)(B_ * S_) * (2 * D_);   // 2*12*64*2048
    __bf16* attn_bf = vt + (size_t)B_ * H_ * HD_ * S_;      // 4096*768

    // 1) fp32 -> bf16
    to_bf16_3<<<(NHS + NWQ + NWO) / 1024, 256, 0, stream>>>(
        hs, wqkv, wo, hs_bf, wqkv_bf, wo_bf);

    // 2) qkv = hs @ Wqkv^T  (q,k -> RoPE fused -> qkv bf16; v -> vt transposed)
    gemm_as<1><<<dim3((3 * D_) / BN, (B_ * S_) / BM), 256, 0, stream>>>(
        hs_bf, wqkv_bf, nullptr, qkv, vt, pos, B_ * S_, 3 * D_, D_);

    // 3) banded MFMA attention
    attn_mfma<<<dim3(S_ / 64, H_, B_), 256, 0, stream>>>(qkv, vt, attn_bf);

    // 4) out = attn @ Wo^T (fp32 out)
    gemm_as<0><<<dim3(D_ / BN, (B_ * S_) / BM), 256, 0, stream>>>(
        attn_bf, wo_bf, out, nullptr, nullptr, nullptr, B_ * S_, D_, D_);
}

// Round 4
// 177.744 us; speedup vs baseline: 1.0068x; 1.0068x over previous
//
#include <hip/hip_runtime.h>
#include <hip/hip_bf16.h>
#include <cmath>

#define B_   2
#define S_   2048
#define D_   768
#define H_   12
#define HD_  64
#define WIN_ 64

typedef __bf16 bf16x8 __attribute__((ext_vector_type(8)));
typedef __bf16 bf16x4 __attribute__((ext_vector_type(4)));
typedef float  f32x4  __attribute__((ext_vector_type(4)));
typedef unsigned int u32;

// async global->LDS, 16B per lane.  LDS dest must be wave-uniform base + lane*16.
__device__ __forceinline__ void async_ld16(const void* g, void* l) {
    __builtin_amdgcn_global_load_lds(
        (__attribute__((address_space(1))) void*)(size_t)g,
        (__attribute__((address_space(3))) void*)(u32)(size_t)l,
        16, 0, 0);
}

// ---------------------------------------------------------------------------
// fp32 -> bf16 convert for hs / Wqkv / Wo (one pass)
// ---------------------------------------------------------------------------
#define NHS (B_ * S_ * D_)        // 3145728
#define NWQ (3 * D_ * D_)         // 1769472
#define NWO (D_ * D_)             //  589824

__global__ __launch_bounds__(256) void to_bf16_3(const float* __restrict__ a,
                                                 const float* __restrict__ b,
                                                 const float* __restrict__ c,
                                                 __bf16* __restrict__ oa,
                                                 __bf16* __restrict__ ob,
                                                 __bf16* __restrict__ oc) {
    const int NA = NHS / 4, NB = NWQ / 4;
    int v = blockIdx.x * 256 + threadIdx.x;
    const float* src; __bf16* dst; int idx;
    if (v < NA)           { src = a; dst = oa; idx = v; }
    else if (v < NA + NB) { src = b; dst = ob; idx = v - NA; }
    else                  { src = c; dst = oc; idx = v - NA - NB; }
    float4 x = ((const float4*)src)[idx];
    bf16x4 y = { (__bf16)x.x, (__bf16)x.y, (__bf16)x.z, (__bf16)x.w };
    *(bf16x4*)(dst + (size_t)idx * 4) = y;
}

// ---------------------------------------------------------------------------
// GEMM: C[M,N] = A[M,K] * Bw[N,K]^T, bf16 in, MFMA, async staging, BK=64.
// LDS held as two k-panels of 32 cols (row stride 64 B) -> same bank geometry
// as BK=32 (2-way = free); BK=64 keeps only 12 barrier drains over K=768.
// MODE 0: fp32 C out.
// MODE 1: fused RoPE on q,k -> qkv bf16 (n<1536); v -> vt bf16 transposed.
// ---------------------------------------------------------------------------
#define BM 128
#define BN 128
#define BK 64

template <int MODE>
__global__ __launch_bounds__(256) void gemm_as(const __bf16* __restrict__ A,
                                               const __bf16* __restrict__ Bw,
                                               float* __restrict__ C,
                                               __bf16* __restrict__ qkv,
                                               __bf16* __restrict__ vt,
                                               const int* __restrict__ pos,
                                               int M, int N, int K) {
    __shared__ __attribute__((aligned(16))) __bf16 As[BM * BK];  // [2][128][32]
    __shared__ __attribute__((aligned(16))) __bf16 Bs[BN * BK];

    const int tid  = threadIdx.x;
    const int m0   = blockIdx.y * BM;
    const int n0   = blockIdx.x * BN;
    const int w    = tid >> 6;
    const int lane = tid & 63;
    const int wm   = (w >> 1) * 64;
    const int wn   = (w & 1) * 64;
    const int fr   = lane & 15;
    const int fq   = lane >> 4;

    f32x4 acc[4][4] = {};

    for (int k0 = 0; k0 < K; k0 += BK) {
        #pragma unroll
        for (int i = 0; i < 4; ++i) {
            int c = i * 256 + tid;          // 1024 chunks of 16B per tile
            int ks = c >> 9, row = (c >> 2) & 127, cc = c & 3;
            async_ld16(A  + (size_t)(m0 + row) * K + k0 + ks * 32 + cc * 8, As + c * 8);
            async_ld16(Bw + (size_t)(n0 + row) * K + k0 + ks * 32 + cc * 8, Bs + c * 8);
        }
        __syncthreads();

        #pragma unroll
        for (int ks = 0; ks < 2; ++ks) {
            bf16x8 af[4], bfv[4];
            #pragma unroll
            for (int t = 0; t < 4; ++t) {
                af[t]  = *(const bf16x8*)(As + (ks * 128 + wm + t * 16 + fr) * 32 + fq * 8);
                bfv[t] = *(const bf16x8*)(Bs + (ks * 128 + wn + t * 16 + fr) * 32 + fq * 8);
            }
            #pragma unroll
            for (int ti = 0; ti < 4; ++ti)
                #pragma unroll
                for (int tj = 0; tj < 4; ++tj)
                    acc[ti][tj] = __builtin_amdgcn_mfma_f32_16x16x32_bf16(
                        af[ti], bfv[tj], acc[ti][tj], 0, 0, 0);
        }
        __syncthreads();
    }

    // C/D layout: col = lane&15, row = (lane>>4)*4 + reg
    if (MODE == 0) {
        #pragma unroll
        for (int ti = 0; ti < 4; ++ti)
            #pragma unroll
            for (int tj = 0; tj < 4; ++tj) {
                const int col = n0 + wn + tj * 16 + fr;
                #pragma unroll
                for (int r = 0; r < 4; ++r) {
                    const int row = m0 + wm + ti * 16 + fq * 4 + r;
                    C[(size_t)row * N + col] = acc[ti][tj][r];
                }
            }
    } else {
        if (n0 < 2 * D_) {
            // fused RoPE: wave spans one 64-col head slice; pair (d, d+32)
            // lives in (acc[ti][tjp], acc[ti][tjp+2]), d = tjp*16 + fr.
            const float invf0 = __powf(10000.0f, -(float)fr * (1.0f / 32.0f));
            const float invf1 = __powf(10000.0f, -(float)(16 + fr) * (1.0f / 32.0f));
            #pragma unroll
            for (int ti = 0; ti < 4; ++ti)
                #pragma unroll
                for (int r = 0; r < 4; ++r) {
                    const int row = m0 + wm + ti * 16 + fq * 4 + r;
                    const float p = (float)pos[row];
                    float s0, c0, s1, c1;
                    sincosf(p * invf0, &s0, &c0);
                    sincosf(p * invf1, &s1, &c1);
                    const float a0 = acc[ti][0][r], a1 = acc[ti][2][r];
                    acc[ti][0][r] = a0 * c0 - a1 * s0;
                    acc[ti][2][r] = a1 * c0 + a0 * s0;
                    const float b0 = acc[ti][1][r], b1 = acc[ti][3][r];
                    acc[ti][1][r] = b0 * c1 - b1 * s1;
                    acc[ti][3][r] = b1 * c1 + b0 * s1;
                }
            #pragma unroll
            for (int ti = 0; ti < 4; ++ti)
                #pragma unroll
                for (int tj = 0; tj < 4; ++tj) {
                    const int col = n0 + wn + tj * 16 + fr;
                    #pragma unroll
                    for (int r = 0; r < 4; ++r) {
                        const int row = m0 + wm + ti * 16 + fq * 4 + r;
                        qkv[(size_t)row * (2 * D_) + col] = (__bf16)acc[ti][tj][r];
                    }
                }
        } else {             // v -> vt[b][h][d][token]
            #pragma unroll
            for (int ti = 0; ti < 4; ++ti)
                #pragma unroll
                for (int tj = 0; tj < 4; ++tj) {
                    const int col = n0 + wn + tj * 16 + fr - 2 * D_;
                    const int h = col >> 6, d = col & 63;
                    const int row0 = m0 + wm + ti * 16 + fq * 4;
                    const int bb = row0 >> 11, t0 = row0 & (S_ - 1);
                    bf16x4 pk = { (__bf16)acc[ti][tj][0], (__bf16)acc[ti][tj][1],
                                  (__bf16)acc[ti][tj][2], (__bf16)acc[ti][tj][3] };
                    *(bf16x4*)(vt + ((size_t)((bb * H_ + h) * HD_ + d)) * S_ + t0) = pk;
                }
        }
    }
}

// ---------------------------------------------------------------------------
// MFMA banded attention.  Block = 64 queries x (head, batch), 4 waves.
// LDS (48 KB -> 3 blocks/CU):
//   Ks  [2][192][32]  (12288 el, 24 KB)  -- overlaid by P after scores
//   Vts [6][64][32]   (12288 el, 24 KB)  (V^T: rows = head dim, cols = keys)
// Q frags read directly from global (16B contiguous per lane).
// ---------------------------------------------------------------------------
__global__ __launch_bounds__(256) void attn_mfma(const __bf16* __restrict__ qkv,
                                                 const __bf16* __restrict__ vt,
                                                 __bf16* __restrict__ outb) {
    __shared__ __attribute__((aligned(16))) __bf16 smem[24576];  // 48 KB
    __bf16* Ks  = smem;
    __bf16* Vts = smem + 12288;

    const int i0  = blockIdx.x * 64;
    const int h   = blockIdx.y;
    const int b   = blockIdx.z;
    const int tid = threadIdx.x;
    const int w = tid >> 6, lane = tid & 63;
    const int fr = lane & 15, fq = lane >> 4;
    const int wq0 = w * 16;

    // ---- stage K (1536 chunks), Vt (1536 chunks) via async copy ----
    #pragma unroll
    for (int i = 0; i < 6; ++i) {
        int c = i * 256 + tid;
        int ks = (i >= 3);
        int rem = c - ks * 768;
        int cc = rem & 3, row = rem >> 2;
        int j = i0 - 64 + row; j = min(max(j, 0), S_ - 1);   // clamped addr; masked later
        async_ld16(qkv + ((size_t)b * S_ + j) * (2 * D_) + D_ + h * HD_ + ks * 32 + cc * 8,
                   Ks + c * 8);
    }
    const size_t vbase = (size_t)((b * H_ + h) * HD_) * S_;
    #pragma unroll
    for (int i = 0; i < 6; ++i) {
        int c = i * 256 + tid;
        int ks = c >> 8, rem = c & 255, d = rem >> 2, cc = rem & 3;
        int key = i0 - 64 + ks * 32 + cc * 8;
        key = min(max(key, 0), S_ - 8);                      // clamped addr; masked later
        async_ld16(vt + vbase + (size_t)d * S_ + key, Vts + c * 8);
    }

    // ---- Q frags from global while staging is in flight ----
    const size_t qrow = ((size_t)b * S_ + i0 + wq0 + fr) * (2 * D_) + h * HD_;
    bf16x8 aq[2];
    aq[0] = *(const bf16x8*)(qkv + qrow + fq * 8);
    aq[1] = *(const bf16x8*)(qkv + qrow + 32 + fq * 8);

    __syncthreads();

    // ---- QK^T: S[16 q][192 keys] per wave ----
    f32x4 sc[12] = {};
    #pragma unroll
    for (int nt = 0; nt < 12; ++nt) {
        #pragma unroll
        for (int ks = 0; ks < 2; ++ks) {
            bf16x8 bk = *(const bf16x8*)(Ks + (ks * 192 + nt * 16 + fr) * 32 + fq * 8);
            sc[nt] = __builtin_amdgcn_mfma_f32_16x16x32_bf16(aq[ks], bk, sc[nt], 0, 0, 0);
        }
    }

    // ---- mask + softmax (C layout: col j <- fr, rows q <- fq*4+r) ----
    float mx[4] = { -1e30f, -1e30f, -1e30f, -1e30f };
    #pragma unroll
    for (int nt = 0; nt < 12; ++nt) {
        const int jr = nt * 16 + fr;          // key - (i0-64)
        const int j  = i0 - 64 + jr;
        const bool jv = (j >= 0) && (j < S_);
        #pragma unroll
        for (int r = 0; r < 4; ++r) {
            const int ir = wq0 + fq * 4 + r + 64;   // query - (i0-64)
            const int dd = ir - jr;
            const bool v = jv && (dd <= WIN_) && (dd >= -WIN_);
            sc[nt][r] = v ? sc[nt][r] * 0.125f : -1e30f;
            mx[r] = fmaxf(mx[r], sc[nt][r]);
        }
    }
    #pragma unroll
    for (int r = 0; r < 4; ++r)
        #pragma unroll
        for (int off = 1; off < 16; off <<= 1)
            mx[r] = fmaxf(mx[r], __shfl_xor(mx[r], off, 64));

    float sm[4] = { 0.f, 0.f, 0.f, 0.f };
    #pragma unroll
    for (int nt = 0; nt < 12; ++nt)
        #pragma unroll
        for (int r = 0; r < 4; ++r) {
            float e = __expf(sc[nt][r] - mx[r]);
            sc[nt][r] = e;
            sm[r] += e;
        }
    #pragma unroll
    for (int r = 0; r < 4; ++r) {
        #pragma unroll
        for (int off = 1; off < 16; off <<= 1)
            sm[r] += __shfl_xor(sm[r], off, 64);
        sm[r] = 1.0f / sm[r];
    }

    __syncthreads();   // all waves done reading Ks before P overwrites it

    // ---- write normalized P (bf16) into per-wave [6][16][32] panels over Ks ----
    __bf16* Pw = Ks + w * 3072;
    #pragma unroll
    for (int nt = 0; nt < 12; ++nt) {
        const int ks = nt >> 1, kk = (nt & 1) * 16 + fr;
        #pragma unroll
        for (int r = 0; r < 4; ++r)
            Pw[(ks * 16 + fq * 4 + r) * 32 + kk] = (__bf16)(sc[nt][r] * sm[r]);
    }

    // ---- O = P * V  (A = P [q][k] panels, B = V^T panels) ----
    f32x4 oacc[4] = {};
    #pragma unroll
    for (int ks = 0; ks < 6; ++ks) {
        bf16x8 ap = *(const bf16x8*)(Pw + (ks * 16 + fr) * 32 + fq * 8);
        #pragma unroll
        for (int nt2 = 0; nt2 < 4; ++nt2) {
            bf16x8 bv = *(const bf16x8*)(Vts + (ks * 64 + nt2 * 16 + fr) * 32 + fq * 8);
            oacc[nt2] = __builtin_amdgcn_mfma_f32_16x16x32_bf16(ap, bv, oacc[nt2], 0, 0, 0);
        }
    }

    const size_t obase = ((size_t)b * S_ + i0 + wq0) * D_ + h * HD_;
    #pragma unroll
    for (int nt2 = 0; nt2 < 4; ++nt2)
        #pragma unroll
        for (int r = 0; r < 4; ++r)
            outb[obase + (size_t)(fq * 4 + r) * D_ + nt2 * 16 + fr] = (__bf16)oacc[nt2][r];
}

// ---------------------------------------------------------------------------
extern "C" void kernel_launch(void* const* d_in, const int* in_sizes, int n_in,
                              void* d_out, int out_size, void* d_ws, size_t ws_size,
                              hipStream_t stream) {
    const float* hs   = (const float*)d_in[0];
    const float* wqkv = (const float*)d_in[1];
    const float* wo   = (const float*)d_in[2];
    const int*   pos  = (const int*)d_in[4];
    float* out = (float*)d_out;

    __bf16* base    = (__bf16*)d_ws;
    __bf16* hs_bf   = base;                          // 3,145,728
    __bf16* wqkv_bf = hs_bf + NHS;                   // 1,769,472
    __bf16* wo_bf   = wqkv_bf + NWQ;                 //   589,824
    __bf16* qkv     = wo_bf + NWO;                   // 4096*1536
    __bf16* vt      = qkv + (size_t)(B_ * S_) * (2 * D_);   // 2*12*64*2048
    __bf16* attn_bf = vt + (size_t)B_ * H_ * HD_ * S_;      // 4096*768

    // 1) fp32 -> bf16
    to_bf16_3<<<(NHS + NWQ + NWO) / 1024, 256, 0, stream>>>(
        hs, wqkv, wo, hs_bf, wqkv_bf, wo_bf);

    // 2) qkv = hs @ Wqkv^T  (q,k -> RoPE fused -> qkv bf16; v -> vt transposed)
    gemm_as<1><<<dim3((3 * D_) / BN, (B_ * S_) / BM), 256, 0, stream>>>(
        hs_bf, wqkv_bf, nullptr, qkv, vt, pos, B_ * S_, 3 * D_, D_);

    // 3) banded MFMA attention
    attn_mfma<<<dim3(S_ / 64, H_, B_), 256, 0, stream>>>(qkv, vt, attn_bf);

    // 4) out = attn @ Wo^T (fp32 out)
    gemm_as<0><<<dim3(D_ / BN, (B_ * S_) / BM), 256, 0, stream>>>(
        attn_bf, wo_bf, out, nullptr, nullptr, nullptr, B_ * S_, D_, D_);
}

// Round 5
// 157.233 us; speedup vs baseline: 1.1381x; 1.1305x over previous
//
#include <hip/hip_runtime.h>
#include <hip/hip_bf16.h>
#include <cmath>

#define B_   2
#define S_   2048
#define D_   768
#define H_   12
#define HD_  64
#define WIN_ 64

typedef __bf16 bf16x8 __attribute__((ext_vector_type(8)));
typedef __bf16 bf16x4 __attribute__((ext_vector_type(4)));
typedef float  f32x4  __attribute__((ext_vector_type(4)));
typedef unsigned int u32;

// async global->LDS, 16B per lane.  LDS dest must be wave-uniform base + lane*16.
__device__ __forceinline__ void async_ld16(const void* g, void* l) {
    __builtin_amdgcn_global_load_lds(
        (__attribute__((address_space(1))) void*)(size_t)g,
        (__attribute__((address_space(3))) void*)(u32)(size_t)l,
        16, 0, 0);
}

// ---------------------------------------------------------------------------
// fp32 -> bf16 convert for hs / Wqkv / Wo (one pass)
// ---------------------------------------------------------------------------
#define NHS (B_ * S_ * D_)        // 3145728
#define NWQ (3 * D_ * D_)         // 1769472
#define NWO (D_ * D_)             //  589824

__global__ __launch_bounds__(256) void to_bf16_3(const float* __restrict__ a,
                                                 const float* __restrict__ b,
                                                 const float* __restrict__ c,
                                                 __bf16* __restrict__ oa,
                                                 __bf16* __restrict__ ob,
                                                 __bf16* __restrict__ oc) {
    const int NA = NHS / 4, NB = NWQ / 4;
    int v = blockIdx.x * 256 + threadIdx.x;
    const float* src; __bf16* dst; int idx;
    if (v < NA)           { src = a; dst = oa; idx = v; }
    else if (v < NA + NB) { src = b; dst = ob; idx = v - NA; }
    else                  { src = c; dst = oc; idx = v - NA - NB; }
    float4 x = ((const float4*)src)[idx];
    bf16x4 y = { (__bf16)x.x, (__bf16)x.y, (__bf16)x.z, (__bf16)x.w };
    *(bf16x4*)(dst + (size_t)idx * 4) = y;
}

// ---------------------------------------------------------------------------
// Single-wave GEMM: C[M,N] = A[M,K] * Bw[N,K]^T.  64x64 tile per 1-wave block,
// BK=32.  No cross-wave barriers -> latency hidden by 9-12 independent
// waves/CU.  LDS chunk swizzle (source-side permute, since global_load_lds
// pins the LDS layout): global chunk (row,cc) stored at row*4 + ((cc+(row>>1))&3)
// -> frag reads are 2-way bank aliased (free) instead of 8-way.
// MODE 0: fp32 C out.
// MODE 1: fused RoPE on q,k -> qkv bf16 (n<1536); v -> vt bf16 transposed.
// ---------------------------------------------------------------------------
template <int MODE>
__global__ __launch_bounds__(64, 3) void gemm_w(const __bf16* __restrict__ A,
                                                const __bf16* __restrict__ Bw,
                                                float* __restrict__ C,
                                                __bf16* __restrict__ qkv,
                                                __bf16* __restrict__ vt,
                                                const int* __restrict__ pos,
                                                int M, int N, int K) {
    __shared__ __attribute__((aligned(16))) __bf16 As[64 * 32];
    __shared__ __attribute__((aligned(16))) __bf16 Bs[64 * 32];

    const int lane = threadIdx.x;
    const int m0 = blockIdx.y * 64;
    const int n0 = blockIdx.x * 64;
    const int fr = lane & 15, fq = lane >> 4;
    const int sw = (fq + (fr >> 1)) & 3;      // swizzled chunk-in-row for frags

    f32x4 acc[4][4] = {};

    for (int k0 = 0; k0 < K; k0 += 32) {
        #pragma unroll
        for (int i = 0; i < 4; ++i) {
            const int c = i * 64 + lane;       // LDS chunk index (16B units)
            const int row = c >> 2, ccp = c & 3;
            const int cc = (ccp - (row >> 1)) & 3;   // global chunk to fetch
            async_ld16(A  + (size_t)(m0 + row) * K + k0 + cc * 8, As + c * 8);
            async_ld16(Bw + (size_t)(n0 + row) * K + k0 + cc * 8, Bs + c * 8);
        }
        __syncthreads();   // wave-local: vmcnt drain only, no convoy

        bf16x8 af[4], bfv[4];
        #pragma unroll
        for (int t = 0; t < 4; ++t) {
            af[t]  = *(const bf16x8*)(As + (t * 16 + fr) * 32 + sw * 8);
            bfv[t] = *(const bf16x8*)(Bs + (t * 16 + fr) * 32 + sw * 8);
        }
        #pragma unroll
        for (int ti = 0; ti < 4; ++ti)
            #pragma unroll
            for (int tj = 0; tj < 4; ++tj)
                acc[ti][tj] = __builtin_amdgcn_mfma_f32_16x16x32_bf16(
                    af[ti], bfv[tj], acc[ti][tj], 0, 0, 0);

        __syncthreads();   // frag reads retired before next staging overwrites
    }

    // C/D layout: col = lane&15, row = (lane>>4)*4 + reg
    if (MODE == 0) {
        #pragma unroll
        for (int ti = 0; ti < 4; ++ti)
            #pragma unroll
            for (int tj = 0; tj < 4; ++tj) {
                const int col = n0 + tj * 16 + fr;
                #pragma unroll
                for (int r = 0; r < 4; ++r) {
                    const int row = m0 + ti * 16 + fq * 4 + r;
                    C[(size_t)row * N + col] = acc[ti][tj][r];
                }
            }
    } else {
        if (n0 < 2 * D_) {
            // fused RoPE: block spans one 64-col head slice; pair (d, d+32)
            // lives in (acc[ti][tjp], acc[ti][tjp+2]), d = tjp*16 + fr.
            const float invf0 = __powf(10000.0f, -(float)fr * (1.0f / 32.0f));
            const float invf1 = __powf(10000.0f, -(float)(16 + fr) * (1.0f / 32.0f));
            #pragma unroll
            for (int ti = 0; ti < 4; ++ti)
                #pragma unroll
                for (int r = 0; r < 4; ++r) {
                    const int row = m0 + ti * 16 + fq * 4 + r;
                    const float p = (float)pos[row];
                    float s0, c0, s1, c1;
                    __sincosf(p * invf0, &s0, &c0);
                    __sincosf(p * invf1, &s1, &c1);
                    const float a0 = acc[ti][0][r], a1 = acc[ti][2][r];
                    acc[ti][0][r] = a0 * c0 - a1 * s0;
                    acc[ti][2][r] = a1 * c0 + a0 * s0;
                    const float b0 = acc[ti][1][r], b1 = acc[ti][3][r];
                    acc[ti][1][r] = b0 * c1 - b1 * s1;
                    acc[ti][3][r] = b1 * c1 + b0 * s1;
                }
            #pragma unroll
            for (int ti = 0; ti < 4; ++ti)
                #pragma unroll
                for (int tj = 0; tj < 4; ++tj) {
                    const int col = n0 + tj * 16 + fr;
                    #pragma unroll
                    for (int r = 0; r < 4; ++r) {
                        const int row = m0 + ti * 16 + fq * 4 + r;
                        qkv[(size_t)row * (2 * D_) + col] = (__bf16)acc[ti][tj][r];
                    }
                }
        } else {             // v -> vt[b][h][d][token]
            const int h = (n0 - 2 * D_) >> 6;
            #pragma unroll
            for (int ti = 0; ti < 4; ++ti)
                #pragma unroll
                for (int tj = 0; tj < 4; ++tj) {
                    const int d = tj * 16 + fr;
                    const int row0 = m0 + ti * 16 + fq * 4;
                    const int bb = row0 >> 11, t0 = row0 & (S_ - 1);
                    bf16x4 pk = { (__bf16)acc[ti][tj][0], (__bf16)acc[ti][tj][1],
                                  (__bf16)acc[ti][tj][2], (__bf16)acc[ti][tj][3] };
                    *(bf16x4*)(vt + ((size_t)((bb * H_ + h) * HD_ + d)) * S_ + t0) = pk;
                }
        }
    }
}

// ---------------------------------------------------------------------------
// MFMA banded attention.  Block = 64 queries x (head, batch), 4 waves.
// LDS (48 KB -> 3 blocks/CU):
//   Ks  [2][192][32]  (12288 el, 24 KB)  -- overlaid by P after scores
//   Vts [6][64][32]   (12288 el, 24 KB)  (V^T: rows = head dim, cols = keys)
// Q frags read directly from global (16B contiguous per lane).
// ---------------------------------------------------------------------------
__global__ __launch_bounds__(256) void attn_mfma(const __bf16* __restrict__ qkv,
                                                 const __bf16* __restrict__ vt,
                                                 __bf16* __restrict__ outb) {
    __shared__ __attribute__((aligned(16))) __bf16 smem[24576];  // 48 KB
    __bf16* Ks  = smem;
    __bf16* Vts = smem + 12288;

    const int i0  = blockIdx.x * 64;
    const int h   = blockIdx.y;
    const int b   = blockIdx.z;
    const int tid = threadIdx.x;
    const int w = tid >> 6, lane = tid & 63;
    const int fr = lane & 15, fq = lane >> 4;
    const int wq0 = w * 16;

    // ---- stage K (1536 chunks), Vt (1536 chunks) via async copy ----
    #pragma unroll
    for (int i = 0; i < 6; ++i) {
        int c = i * 256 + tid;
        int ks = (i >= 3);
        int rem = c - ks * 768;
        int cc = rem & 3, row = rem >> 2;
        int j = i0 - 64 + row; j = min(max(j, 0), S_ - 1);   // clamped addr; masked later
        async_ld16(qkv + ((size_t)b * S_ + j) * (2 * D_) + D_ + h * HD_ + ks * 32 + cc * 8,
                   Ks + c * 8);
    }
    const size_t vbase = (size_t)((b * H_ + h) * HD_) * S_;
    #pragma unroll
    for (int i = 0; i < 6; ++i) {
        int c = i * 256 + tid;
        int ks = c >> 8, rem = c & 255, d = rem >> 2, cc = rem & 3;
        int key = i0 - 64 + ks * 32 + cc * 8;
        key = min(max(key, 0), S_ - 8);                      // clamped addr; masked later
        async_ld16(vt + vbase + (size_t)d * S_ + key, Vts + c * 8);
    }

    // ---- Q frags from global while staging is in flight ----
    const size_t qrow = ((size_t)b * S_ + i0 + wq0 + fr) * (2 * D_) + h * HD_;
    bf16x8 aq[2];
    aq[0] = *(const bf16x8*)(qkv + qrow + fq * 8);
    aq[1] = *(const bf16x8*)(qkv + qrow + 32 + fq * 8);

    __syncthreads();

    // ---- QK^T: S[16 q][192 keys] per wave ----
    f32x4 sc[12] = {};
    #pragma unroll
    for (int nt = 0; nt < 12; ++nt) {
        #pragma unroll
        for (int ks = 0; ks < 2; ++ks) {
            bf16x8 bk = *(const bf16x8*)(Ks + (ks * 192 + nt * 16 + fr) * 32 + fq * 8);
            sc[nt] = __builtin_amdgcn_mfma_f32_16x16x32_bf16(aq[ks], bk, sc[nt], 0, 0, 0);
        }
    }

    // ---- mask + softmax (C layout: col j <- fr, rows q <- fq*4+r) ----
    float mx[4] = { -1e30f, -1e30f, -1e30f, -1e30f };
    #pragma unroll
    for (int nt = 0; nt < 12; ++nt) {
        const int jr = nt * 16 + fr;          // key - (i0-64)
        const int j  = i0 - 64 + jr;
        const bool jv = (j >= 0) && (j < S_);
        #pragma unroll
        for (int r = 0; r < 4; ++r) {
            const int ir = wq0 + fq * 4 + r + 64;   // query - (i0-64)
            const int dd = ir - jr;
            const bool v = jv && (dd <= WIN_) && (dd >= -WIN_);
            sc[nt][r] = v ? sc[nt][r] * 0.125f : -1e30f;
            mx[r] = fmaxf(mx[r], sc[nt][r]);
        }
    }
    #pragma unroll
    for (int r = 0; r < 4; ++r)
        #pragma unroll
        for (int off = 1; off < 16; off <<= 1)
            mx[r] = fmaxf(mx[r], __shfl_xor(mx[r], off, 64));

    float sm[4] = { 0.f, 0.f, 0.f, 0.f };
    #pragma unroll
    for (int nt = 0; nt < 12; ++nt)
        #pragma unroll
        for (int r = 0; r < 4; ++r) {
            float e = __expf(sc[nt][r] - mx[r]);
            sc[nt][r] = e;
            sm[r] += e;
        }
    #pragma unroll
    for (int r = 0; r < 4; ++r) {
        #pragma unroll
        for (int off = 1; off < 16; off <<= 1)
            sm[r] += __shfl_xor(sm[r], off, 64);
        sm[r] = 1.0f / sm[r];
    }

    __syncthreads();   // all waves done reading Ks before P overwrites it

    // ---- write normalized P (bf16) into per-wave [6][16][32] panels over Ks ----
    __bf16* Pw = Ks + w * 3072;
    #pragma unroll
    for (int nt = 0; nt < 12; ++nt) {
        const int ks = nt >> 1, kk = (nt & 1) * 16 + fr;
        #pragma unroll
        for (int r = 0; r < 4; ++r)
            Pw[(ks * 16 + fq * 4 + r) * 32 + kk] = (__bf16)(sc[nt][r] * sm[r]);
    }

    // ---- O = P * V  (A = P [q][k] panels, B = V^T panels) ----
    f32x4 oacc[4] = {};
    #pragma unroll
    for (int ks = 0; ks < 6; ++ks) {
        bf16x8 ap = *(const bf16x8*)(Pw + (ks * 16 + fr) * 32 + fq * 8);
        #pragma unroll
        for (int nt2 = 0; nt2 < 4; ++nt2) {
            bf16x8 bv = *(const bf16x8*)(Vts + (ks * 64 + nt2 * 16 + fr) * 32 + fq * 8);
            oacc[nt2] = __builtin_amdgcn_mfma_f32_16x16x32_bf16(ap, bv, oacc[nt2], 0, 0, 0);
        }
    }

    const size_t obase = ((size_t)b * S_ + i0 + wq0) * D_ + h * HD_;
    #pragma unroll
    for (int nt2 = 0; nt2 < 4; ++nt2)
        #pragma unroll
        for (int r = 0; r < 4; ++r)
            outb[obase + (size_t)(fq * 4 + r) * D_ + nt2 * 16 + fr] = (__bf16)oacc[nt2][r];
}

// ---------------------------------------------------------------------------
extern "C" void kernel_launch(void* const* d_in, const int* in_sizes, int n_in,
                              void* d_out, int out_size, void* d_ws, size_t ws_size,
                              hipStream_t stream) {
    const float* hs   = (const float*)d_in[0];
    const float* wqkv = (const float*)d_in[1];
    const float* wo   = (const float*)d_in[2];
    const int*   pos  = (const int*)d_in[4];
    float* out = (float*)d_out;

    __bf16* base    = (__bf16*)d_ws;
    __bf16* hs_bf   = base;                          // 3,145,728
    __bf16* wqkv_bf = hs_bf + NHS;                   // 1,769,472
    __bf16* wo_bf   = wqkv_bf + NWQ;                 //   589,824
    __bf16* qkv     = wo_bf + NWO;                   // 4096*1536
    __bf16* vt      = qkv + (size_t)(B_ * S_) * (2 * D_);   // 2*12*64*2048
    __bf16* attn_bf = vt + (size_t)B_ * H_ * HD_ * S_;      // 4096*768

    // 1) fp32 -> bf16
    to_bf16_3<<<(NHS + NWQ + NWO) / 1024, 256, 0, stream>>>(
        hs, wqkv, wo, hs_bf, wqkv_bf, wo_bf);

    // 2) qkv = hs @ Wqkv^T  (q,k -> RoPE fused -> qkv bf16; v -> vt transposed)
    gemm_w<1><<<dim3((3 * D_) / 64, (B_ * S_) / 64), 64, 0, stream>>>(
        hs_bf, wqkv_bf, nullptr, qkv, vt, pos, B_ * S_, 3 * D_, D_);

    // 3) banded MFMA attention
    attn_mfma<<<dim3(S_ / 64, H_, B_), 256, 0, stream>>>(qkv, vt, attn_bf);

    // 4) out = attn @ Wo^T (fp32 out)
    gemm_w<0><<<dim3(D_ / 64, (B_ * S_) / 64), 64, 0, stream>>>(
        attn_bf, wo_bf, out, nullptr, nullptr, nullptr, B_ * S_, D_, D_);
}

// Round 6
// 150.947 us; speedup vs baseline: 1.1855x; 1.0416x over previous
//
#include <hip/hip_runtime.h>
#include <hip/hip_bf16.h>
#include <cmath>

#define B_   2
#define S_   2048
#define D_   768
#define H_   12
#define HD_  64
#define WIN_ 64

typedef __bf16 bf16x8 __attribute__((ext_vector_type(8)));
typedef __bf16 bf16x4 __attribute__((ext_vector_type(4)));
typedef float  f32x4  __attribute__((ext_vector_type(4)));
typedef unsigned int u32;

// async global->LDS, 16B per lane.  LDS dest must be wave-uniform base + lane*16.
__device__ __forceinline__ void async_ld16(const void* g, void* l) {
    __builtin_amdgcn_global_load_lds(
        (__attribute__((address_space(1))) void*)(size_t)g,
        (__attribute__((address_space(3))) void*)(u32)(size_t)l,
        16, 0, 0);
}

// s_waitcnt immediates (gfx9 encoding): vmcnt[3:0] | expcnt<<4 | lgkmcnt<<8
#define WAITCNT_VM8 0xF78   // vmcnt(8), lgkm/exp no-wait
#define WAITCNT_VM0 0xF70   // vmcnt(0), lgkm/exp no-wait

// ---------------------------------------------------------------------------
// fp32 -> bf16 convert for hs / Wqkv / Wo (one pass)
// ---------------------------------------------------------------------------
#define NHS (B_ * S_ * D_)        // 3145728
#define NWQ (3 * D_ * D_)         // 1769472
#define NWO (D_ * D_)             //  589824

__global__ __launch_bounds__(256) void to_bf16_3(const float* __restrict__ a,
                                                 const float* __restrict__ b,
                                                 const float* __restrict__ c,
                                                 __bf16* __restrict__ oa,
                                                 __bf16* __restrict__ ob,
                                                 __bf16* __restrict__ oc) {
    const int NA = NHS / 4, NB = NWQ / 4;
    int v = blockIdx.x * 256 + threadIdx.x;
    const float* src; __bf16* dst; int idx;
    if (v < NA)           { src = a; dst = oa; idx = v; }
    else if (v < NA + NB) { src = b; dst = ob; idx = v - NA; }
    else                  { src = c; dst = oc; idx = v - NA - NB; }
    float4 x = ((const float4*)src)[idx];
    bf16x4 y = { (__bf16)x.x, (__bf16)x.y, (__bf16)x.z, (__bf16)x.w };
    *(bf16x4*)(dst + (size_t)idx * 4) = y;
}

// ---------------------------------------------------------------------------
// Single-wave pipelined GEMM: C[M,N] = A[M,K] * Bw[N,K]^T.  64x64 tile,
// BK=32, double-buffered LDS, NO barriers (single wave): prefetch iter k+1
// while computing iter k, gated by explicit s_waitcnt vmcnt(8).
// Source-side chunk swizzle keeps frag ds_read_b128 at 2-way bank alias.
// MODE 0: fp32 C out.
// MODE 1: fused RoPE on q,k -> qkv bf16 (n<1536); v -> vt bf16 transposed.
// ---------------------------------------------------------------------------
template <int MODE>
__global__ __launch_bounds__(64) void gemm_w(const __bf16* __restrict__ A,
                                             const __bf16* __restrict__ Bw,
                                             float* __restrict__ C,
                                             __bf16* __restrict__ qkv,
                                             __bf16* __restrict__ vt,
                                             const int* __restrict__ pos,
                                             int M, int N, int K) {
    __shared__ __attribute__((aligned(16))) __bf16 As[2][64 * 32];
    __shared__ __attribute__((aligned(16))) __bf16 Bs[2][64 * 32];

    const int lane = threadIdx.x;
    const int m0 = blockIdx.y * 64;
    const int n0 = blockIdx.x * 64;
    const int fr = lane & 15, fq = lane >> 4;
    const int sw = (fq + (fr >> 1)) & 3;      // swizzled chunk-in-row for frags

    // per-lane staging geometry (4 chunks per tile per lane)
    const int row_[4] = { (lane >> 2), (64 + lane) >> 2, (128 + lane) >> 2, (192 + lane) >> 2 };

    auto issue = [&](int k0, int p) {
        #pragma unroll
        for (int i = 0; i < 4; ++i) {
            const int c = i * 64 + lane;
            const int row = c >> 2, ccp = c & 3;
            const int cc = (ccp - (row >> 1)) & 3;   // source chunk permute
            async_ld16(A  + (size_t)(m0 + row) * K + k0 + cc * 8, &As[p][c * 8]);
            async_ld16(Bw + (size_t)(n0 + row) * K + k0 + cc * 8, &Bs[p][c * 8]);
        }
    };

    f32x4 acc[4][4] = {};
    const int nk = K >> 5;                    // 24 for K=768

    issue(0, 0);
    issue(32, 1);

    for (int k = 0; k < nk - 1; ++k) {
        __builtin_amdgcn_s_waitcnt(WAITCNT_VM8);   // iter k's 8 loads landed
        const int p = k & 1;
        bf16x8 af[4], bfv[4];
        #pragma unroll
        for (int t = 0; t < 4; ++t) {
            af[t]  = *(const bf16x8*)(&As[p][(t * 16 + fr) * 32 + sw * 8]);
            bfv[t] = *(const bf16x8*)(&Bs[p][(t * 16 + fr) * 32 + sw * 8]);
        }
        if (k + 2 < nk) issue((k + 2) << 5, p);    // refill the buffer just read
        #pragma unroll
        for (int ti = 0; ti < 4; ++ti)
            #pragma unroll
            for (int tj = 0; tj < 4; ++tj)
                acc[ti][tj] = __builtin_amdgcn_mfma_f32_16x16x32_bf16(
                    af[ti], bfv[tj], acc[ti][tj], 0, 0, 0);
    }
    {   // peeled last iteration: nothing left in flight to spare
        __builtin_amdgcn_s_waitcnt(WAITCNT_VM0);
        const int p = (nk - 1) & 1;
        bf16x8 af[4], bfv[4];
        #pragma unroll
        for (int t = 0; t < 4; ++t) {
            af[t]  = *(const bf16x8*)(&As[p][(t * 16 + fr) * 32 + sw * 8]);
            bfv[t] = *(const bf16x8*)(&Bs[p][(t * 16 + fr) * 32 + sw * 8]);
        }
        #pragma unroll
        for (int ti = 0; ti < 4; ++ti)
            #pragma unroll
            for (int tj = 0; tj < 4; ++tj)
                acc[ti][tj] = __builtin_amdgcn_mfma_f32_16x16x32_bf16(
                    af[ti], bfv[tj], acc[ti][tj], 0, 0, 0);
    }

    // C/D layout: col = lane&15, row = (lane>>4)*4 + reg
    if (MODE == 0) {
        #pragma unroll
        for (int ti = 0; ti < 4; ++ti)
            #pragma unroll
            for (int tj = 0; tj < 4; ++tj) {
                const int col = n0 + tj * 16 + fr;
                #pragma unroll
                for (int r = 0; r < 4; ++r) {
                    const int row = m0 + ti * 16 + fq * 4 + r;
                    C[(size_t)row * N + col] = acc[ti][tj][r];
                }
            }
    } else {
        if (n0 < 2 * D_) {
            // fused RoPE: block spans one 64-col head slice; pair (d, d+32)
            // lives in (acc[ti][tjp], acc[ti][tjp+2]), d = tjp*16 + fr.
            const float invf0 = __powf(10000.0f, -(float)fr * (1.0f / 32.0f));
            const float invf1 = __powf(10000.0f, -(float)(16 + fr) * (1.0f / 32.0f));
            #pragma unroll
            for (int ti = 0; ti < 4; ++ti)
                #pragma unroll
                for (int r = 0; r < 4; ++r) {
                    const int row = m0 + ti * 16 + fq * 4 + r;
                    const float p = (float)pos[row];
                    float s0, c0, s1, c1;
                    __sincosf(p * invf0, &s0, &c0);
                    __sincosf(p * invf1, &s1, &c1);
                    const float a0 = acc[ti][0][r], a1 = acc[ti][2][r];
                    acc[ti][0][r] = a0 * c0 - a1 * s0;
                    acc[ti][2][r] = a1 * c0 + a0 * s0;
                    const float b0 = acc[ti][1][r], b1 = acc[ti][3][r];
                    acc[ti][1][r] = b0 * c1 - b1 * s1;
                    acc[ti][3][r] = b1 * c1 + b0 * s1;
                }
            #pragma unroll
            for (int ti = 0; ti < 4; ++ti)
                #pragma unroll
                for (int tj = 0; tj < 4; ++tj) {
                    const int col = n0 + tj * 16 + fr;
                    #pragma unroll
                    for (int r = 0; r < 4; ++r) {
                        const int row = m0 + ti * 16 + fq * 4 + r;
                        qkv[(size_t)row * (2 * D_) + col] = (__bf16)acc[ti][tj][r];
                    }
                }
        } else {             // v -> vt[b][h][d][token]
            const int h = (n0 - 2 * D_) >> 6;
            #pragma unroll
            for (int ti = 0; ti < 4; ++ti)
                #pragma unroll
                for (int tj = 0; tj < 4; ++tj) {
                    const int d = tj * 16 + fr;
                    const int row0 = m0 + ti * 16 + fq * 4;
                    const int bb = row0 >> 11, t0 = row0 & (S_ - 1);
                    bf16x4 pk = { (__bf16)acc[ti][tj][0], (__bf16)acc[ti][tj][1],
                                  (__bf16)acc[ti][tj][2], (__bf16)acc[ti][tj][3] };
                    *(bf16x4*)(vt + ((size_t)((bb * H_ + h) * HD_ + d)) * S_ + t0) = pk;
                }
        }
    }
}

// ---------------------------------------------------------------------------
// MFMA banded attention.  Block = 64 queries x (head, batch), 4 waves.
// LDS (48 KB -> 3 blocks/CU):
//   Ks  [2][192][32]  (12288 el, 24 KB)  -- overlaid by P after scores
//   Vts [6][64][32]   (12288 el, 24 KB)  (V^T: rows = head dim, cols = keys)
// Q frags read directly from global (16B contiguous per lane).
// ---------------------------------------------------------------------------
__global__ __launch_bounds__(256) void attn_mfma(const __bf16* __restrict__ qkv,
                                                 const __bf16* __restrict__ vt,
                                                 __bf16* __restrict__ outb) {
    __shared__ __attribute__((aligned(16))) __bf16 smem[24576];  // 48 KB
    __bf16* Ks  = smem;
    __bf16* Vts = smem + 12288;

    const int i0  = blockIdx.x * 64;
    const int h   = blockIdx.y;
    const int b   = blockIdx.z;
    const int tid = threadIdx.x;
    const int w = tid >> 6, lane = tid & 63;
    const int fr = lane & 15, fq = lane >> 4;
    const int wq0 = w * 16;

    // ---- stage K (1536 chunks), Vt (1536 chunks) via async copy ----
    #pragma unroll
    for (int i = 0; i < 6; ++i) {
        int c = i * 256 + tid;
        int ks = (i >= 3);
        int rem = c - ks * 768;
        int cc = rem & 3, row = rem >> 2;
        int j = i0 - 64 + row; j = min(max(j, 0), S_ - 1);   // clamped addr; masked later
        async_ld16(qkv + ((size_t)b * S_ + j) * (2 * D_) + D_ + h * HD_ + ks * 32 + cc * 8,
                   Ks + c * 8);
    }
    const size_t vbase = (size_t)((b * H_ + h) * HD_) * S_;
    #pragma unroll
    for (int i = 0; i < 6; ++i) {
        int c = i * 256 + tid;
        int ks = c >> 8, rem = c & 255, d = rem >> 2, cc = rem & 3;
        int key = i0 - 64 + ks * 32 + cc * 8;
        key = min(max(key, 0), S_ - 8);                      // clamped addr; masked later
        async_ld16(vt + vbase + (size_t)d * S_ + key, Vts + c * 8);
    }

    // ---- Q frags from global while staging is in flight ----
    const size_t qrow = ((size_t)b * S_ + i0 + wq0 + fr) * (2 * D_) + h * HD_;
    bf16x8 aq[2];
    aq[0] = *(const bf16x8*)(qkv + qrow + fq * 8);
    aq[1] = *(const bf16x8*)(qkv + qrow + 32 + fq * 8);

    __syncthreads();

    // ---- QK^T: S[16 q][192 keys] per wave ----
    f32x4 sc[12] = {};
    #pragma unroll
    for (int nt = 0; nt < 12; ++nt) {
        #pragma unroll
        for (int ks = 0; ks < 2; ++ks) {
            bf16x8 bk = *(const bf16x8*)(Ks + (ks * 192 + nt * 16 + fr) * 32 + fq * 8);
            sc[nt] = __builtin_amdgcn_mfma_f32_16x16x32_bf16(aq[ks], bk, sc[nt], 0, 0, 0);
        }
    }

    // ---- mask + softmax (C layout: col j <- fr, rows q <- fq*4+r) ----
    float mx[4] = { -1e30f, -1e30f, -1e30f, -1e30f };
    #pragma unroll
    for (int nt = 0; nt < 12; ++nt) {
        const int jr = nt * 16 + fr;          // key - (i0-64)
        const int j  = i0 - 64 + jr;
        const bool jv = (j >= 0) && (j < S_);
        #pragma unroll
        for (int r = 0; r < 4; ++r) {
            const int ir = wq0 + fq * 4 + r + 64;   // query - (i0-64)
            const int dd = ir - jr;
            const bool v = jv && (dd <= WIN_) && (dd >= -WIN_);
            sc[nt][r] = v ? sc[nt][r] * 0.125f : -1e30f;
            mx[r] = fmaxf(mx[r], sc[nt][r]);
        }
    }
    #pragma unroll
    for (int r = 0; r < 4; ++r)
        #pragma unroll
        for (int off = 1; off < 16; off <<= 1)
            mx[r] = fmaxf(mx[r], __shfl_xor(mx[r], off, 64));

    float sm[4] = { 0.f, 0.f, 0.f, 0.f };
    #pragma unroll
    for (int nt = 0; nt < 12; ++nt)
        #pragma unroll
        for (int r = 0; r < 4; ++r) {
            float e = __expf(sc[nt][r] - mx[r]);
            sc[nt][r] = e;
            sm[r] += e;
        }
    #pragma unroll
    for (int r = 0; r < 4; ++r) {
        #pragma unroll
        for (int off = 1; off < 16; off <<= 1)
            sm[r] += __shfl_xor(sm[r], off, 64);
        sm[r] = 1.0f / sm[r];
    }

    __syncthreads();   // all waves done reading Ks before P overwrites it

    // ---- write normalized P (bf16) into per-wave [6][16][32] panels over Ks ----
    __bf16* Pw = Ks + w * 3072;
    #pragma unroll
    for (int nt = 0; nt < 12; ++nt) {
        const int ks = nt >> 1, kk = (nt & 1) * 16 + fr;
        #pragma unroll
        for (int r = 0; r < 4; ++r)
            Pw[(ks * 16 + fq * 4 + r) * 32 + kk] = (__bf16)(sc[nt][r] * sm[r]);
    }

    // ---- O = P * V  (A = P [q][k] panels, B = V^T panels) ----
    f32x4 oacc[4] = {};
    #pragma unroll
    for (int ks = 0; ks < 6; ++ks) {
        bf16x8 ap = *(const bf16x8*)(Pw + (ks * 16 + fr) * 32 + fq * 8);
        #pragma unroll
        for (int nt2 = 0; nt2 < 4; ++nt2) {
            bf16x8 bv = *(const bf16x8*)(Vts + (ks * 64 + nt2 * 16 + fr) * 32 + fq * 8);
            oacc[nt2] = __builtin_amdgcn_mfma_f32_16x16x32_bf16(ap, bv, oacc[nt2], 0, 0, 0);
        }
    }

    const size_t obase = ((size_t)b * S_ + i0 + wq0) * D_ + h * HD_;
    #pragma unroll
    for (int nt2 = 0; nt2 < 4; ++nt2)
        #pragma unroll
        for (int r = 0; r < 4; ++r)
            outb[obase + (size_t)(fq * 4 + r) * D_ + nt2 * 16 + fr] = (__bf16)oacc[nt2][r];
}

// ---------------------------------------------------------------------------
extern "C" void kernel_launch(void* const* d_in, const int* in_sizes, int n_in,
                              void* d_out, int out_size, void* d_ws, size_t ws_size,
                              hipStream_t stream) {
    const float* hs   = (const float*)d_in[0];
    const float* wqkv = (const float*)d_in[1];
    const float* wo   = (const float*)d_in[2];
    const int*   pos  = (const int*)d_in[4];
    float* out = (float*)d_out;

    __bf16* base    = (__bf16*)d_ws;
    __bf16* hs_bf   = base;                          // 3,145,728
    __bf16* wqkv_bf = hs_bf + NHS;                   // 1,769,472
    __bf16* wo_bf   = wqkv_bf + NWQ;                 //   589,824
    __bf16* qkv     = wo_bf + NWO;                   // 4096*1536
    __bf16* vt      = qkv + (size_t)(B_ * S_) * (2 * D_);   // 2*12*64*2048
    __bf16* attn_bf = vt + (size_t)B_ * H_ * HD_ * S_;      // 4096*768

    // 1) fp32 -> bf16
    to_bf16_3<<<(NHS + NWQ + NWO) / 1024, 256, 0, stream>>>(
        hs, wqkv, wo, hs_bf, wqkv_bf, wo_bf);

    // 2) qkv = hs @ Wqkv^T  (q,k -> RoPE fused -> qkv bf16; v -> vt transposed)
    gemm_w<1><<<dim3((3 * D_) / 64, (B_ * S_) / 64), 64, 0, stream>>>(
        hs_bf, wqkv_bf, nullptr, qkv, vt, pos, B_ * S_, 3 * D_, D_);

    // 3) banded MFMA attention
    attn_mfma<<<dim3(S_ / 64, H_, B_), 256, 0, stream>>>(qkv, vt, attn_bf);

    // 4) out = attn @ Wo^T (fp32 out)
    gemm_w<0><<<dim3(D_ / 64, (B_ * S_) / 64), 64, 0, stream>>>(
        attn_bf, wo_bf, out, nullptr, nullptr, nullptr, B_ * S_, D_, D_);
}